// Round 5
// baseline (1728.517 us; speedup 1.0000x reference)
//
#include <hip/hip_runtime.h>
#include <hip/hip_bf16.h>

#define NROWS 65536
#define LN_EPS 1e-5f

typedef __attribute__((ext_vector_type(8))) short bf16x8;
typedef __attribute__((ext_vector_type(4))) float f32x4;

__device__ __forceinline__ float bf2f(unsigned short u) {
  union { unsigned u; float f; } c; c.u = ((unsigned)u) << 16; return c.f;
}
__device__ __forceinline__ unsigned short f2bf(float f) {
  union { float f; unsigned u; } c; c.f = f;
  return (unsigned short)((c.u + 0x7fffu + ((c.u >> 16) & 1u)) >> 16);
}

// ---- row LN stats + normalize + cast to bf16: o[row] = (x[row]-mean)*rstd --
__launch_bounds__(256)
__global__ void normcast_k(const float* __restrict__ x, unsigned short* __restrict__ o) {
  int t = threadIdx.x;
  int row = blockIdx.x * 4 + (t >> 6);
  int lane = t & 63;
  const float* p = x + (size_t)row * 512 + lane * 8;
  float4 a = *(const float4*)p;
  float4 b = *(const float4*)(p + 4);
  float s = a.x + a.y + a.z + a.w + b.x + b.y + b.z + b.w;
  float q = a.x*a.x + a.y*a.y + a.z*a.z + a.w*a.w
          + b.x*b.x + b.y*b.y + b.z*b.z + b.w*b.w;
#pragma unroll
  for (int off = 1; off < 64; off <<= 1) {
    s += __shfl_xor(s, off);
    q += __shfl_xor(q, off);
  }
  float mean = s * (1.0f / 512.0f);
  float r = rsqrtf(q * (1.0f / 512.0f) - mean * mean + LN_EPS);
  float va[8] = {a.x, a.y, a.z, a.w, b.x, b.y, b.z, b.w};
  unsigned pk[4];
#pragma unroll
  for (int i = 0; i < 4; ++i) {
    unsigned lo = f2bf((va[2 * i] - mean) * r);
    unsigned hi = f2bf((va[2 * i + 1] - mean) * r);
    pk[i] = lo | (hi << 16);
  }
  uint4 u; u.x = pk[0]; u.y = pk[1]; u.z = pk[2]; u.w = pk[3];
  *(uint4*)(o + (size_t)row * 512 + lane * 8) = u;
}

// ---- transpose + optional per-K-row scale, fp32 -> bf16:  Wt[n,k]=g[k]*W[k,n]
__launch_bounds__(256)
__global__ void transbf_k(const float* __restrict__ W, const float* __restrict__ g,
                          unsigned short* __restrict__ Wt, int K, int N) {
  __shared__ float tile[32][33];
  int tx = threadIdx.x & 31, ty = threadIdx.x >> 5;
  int n0 = blockIdx.x * 32, k0 = blockIdx.y * 32;
#pragma unroll
  for (int i = 0; i < 4; ++i) {
    int k = k0 + ty + i * 8;
    float gg = g ? g[k] : 1.0f;
    tile[ty + i * 8][tx] = gg * W[(size_t)k * N + n0 + tx];
  }
  __syncthreads();
#pragma unroll
  for (int i = 0; i < 4; ++i) {
    int n = n0 + ty + i * 8;
    Wt[(size_t)n * K + k0 + tx] = f2bf(tile[tx][ty + i * 8]);
  }
}

// ---- beta[n] = sum_k b[k]*W[k,n] + bias[n] --------------------------------
__launch_bounds__(256)
__global__ void betacalc_k(const float* __restrict__ W, const float* __restrict__ b,
                           const float* __restrict__ bias, float* __restrict__ beta,
                           int K, int N) {
  int n = blockIdx.x * 256 + threadIdx.x;
  float s = 0.f;
  for (int k = 0; k < K; ++k) s += b[k] * W[(size_t)k * N + n];
  beta[n] = s + bias[n];
}

// ---- MFMA GEMM: C[M,N] = A[M,K](bf16) @ Bt[N,K](bf16)^T + beta, + epilogue -
#define M_Q  0  // out bf16, reduce sum(v^2) -> scal
#define M_KV 1  // paired K/V 64-col groups; V->bf16 out, K only reduced (S1,S2,scal)
#define M_H  3  // out fp32 = acc + beta + src (residual)
#define M_F1 4  // out bf16 = gelu(acc + beta); TRANSPOSED acc, wide stores
#define M_F2 5  // out fp32 += acc + beta

template <int MODE>
__launch_bounds__(256)
__global__ void mm_k(const unsigned short* __restrict__ A,
                     const unsigned short* __restrict__ Bt,
                     void* __restrict__ Ov,
                     const float* __restrict__ beta,
                     const float* __restrict__ src,
                     float* __restrict__ scal,
                     float* __restrict__ S1,
                     float* __restrict__ S2,
                     int N, int K) {
  // single allocation so the M_KV epilogue can overlay a [128][64] fp32 tile
  __shared__ __align__(16) unsigned short AsBs[2 * 128 * 64];
  __shared__ float red[4];
  unsigned short* As = AsBs;
  unsigned short* Bs = AsBs + 128 * 64;
  const int t = threadIdx.x;
  const int lane = t & 63;
  const int wave = t >> 6;

  // T1: XCD-chunked bijective swizzle (nwg % 8 == 0 for all our grids).
  const unsigned gx = gridDim.x;
  unsigned bid = blockIdx.y * gx + blockIdx.x;
  const unsigned cpx = (gx * gridDim.y) >> 3;
  bid = (bid & 7u) * cpx + (bid >> 3);
  const int m0 = (int)(bid / gx) * 128;
  const int n0 = (int)(bid % gx) * 128;
  const int g64 = n0 >> 1;  // M_KV: 64-col group offset (block bx covers K and V cols g64..g64+63)

  const int srow = lane >> 3;                   // 0..7: row within 8-row chunk
  const int sxor = ((lane & 7) ^ srow) * 8;     // swizzled k-offset (elements)
  const int wm = (wave >> 1) * 64;
  const int wn = (wave & 1) * 64;
  const int quad = lane >> 4;
  const int l15 = lane & 15;
  const int l7 = lane & 7;

  f32x4 acc[4][4];
#pragma unroll
  for (int i = 0; i < 4; ++i)
#pragma unroll
    for (int j = 0; j < 4; ++j) acc[i][j] = (f32x4){0.f, 0.f, 0.f, 0.f};

  for (int k0 = 0; k0 < K; k0 += 64) {
    __syncthreads();
#pragma unroll
    for (int i = 0; i < 4; ++i) {
      int c = wave * 4 + i;
      int grow = c * 8 + srow;
      const unsigned short* ga = A + (size_t)(m0 + grow) * K + k0 + sxor;
      const unsigned short* gb;
      if constexpr (MODE == M_KV) {
        // B-tile rows 0..63 = Wk cols g64..g64+63 (Bt rows g64+..),
        //        rows 64..127 = Wv cols g64..g64+63 (Bt rows 512+g64+..)
        int btrow = (c < 8) ? (g64 + grow) : (512 - 64 + g64 + grow);
        gb = Bt + (size_t)btrow * K + k0 + sxor;
      } else {
        gb = Bt + (size_t)(n0 + grow) * K + k0 + sxor;
      }
      __builtin_amdgcn_global_load_lds(
          (const __attribute__((address_space(1))) void*)ga,
          (__attribute__((address_space(3))) void*)(As + c * 512), 16, 0, 0);
      __builtin_amdgcn_global_load_lds(
          (const __attribute__((address_space(1))) void*)gb,
          (__attribute__((address_space(3))) void*)(Bs + c * 512), 16, 0, 0);
    }
    __syncthreads();
#pragma unroll
    for (int kt = 0; kt < 2; ++kt) {
      const int pb = ((kt * 4 + quad) ^ l7) * 8;
      bf16x8 af[4], bfr[4];
#pragma unroll
      for (int x = 0; x < 4; ++x) {
        af[x]  = *(const bf16x8*)(As + (wm + x * 16 + l15) * 64 + pb);
        bfr[x] = *(const bf16x8*)(Bs + (wn + x * 16 + l15) * 64 + pb);
      }
#pragma unroll
      for (int mi = 0; mi < 4; ++mi)
#pragma unroll
        for (int nj = 0; nj < 4; ++nj) {
          if constexpr (MODE == M_F1) {
            // transposed C: row index <- lane&15 (af rows), col <- quad*4+reg
            acc[mi][nj] = __builtin_amdgcn_mfma_f32_16x16x32_bf16(
                bfr[nj], af[mi], acc[mi][nj], 0, 0, 0);
          } else {
            acc[mi][nj] = __builtin_amdgcn_mfma_f32_16x16x32_bf16(
                af[mi], bfr[nj], acc[mi][nj], 0, 0, 0);
          }
        }
    }
  }

  float lred = 0.f;
  if constexpr (MODE == M_KV) {
    // Waves 0,2 hold K (B-rows 0..63); waves 1,3 hold V (B-rows 64..127).
    // Wave pair (0,1) covers local rows 0..63, (2,3) rows 64..127 (same wm).
    float* Vx = (float*)AsBs;  // [128][64] fp32, quad-XOR swizzle: 2-way max
    __syncthreads();           // all LDS reads of the K-loop complete
    if (wn) {
      // V-waves: publish fp32 V to LDS, store bf16 V to global
#pragma unroll
      for (int mi = 0; mi < 4; ++mi) {
#pragma unroll
        for (int nj = 0; nj < 4; ++nj) {
          const int colv = nj * 16 + l15;             // 0..63 within group
          const float bet = beta[512 + g64 + colv];   // betav
          size_t idx = (size_t)(m0 + wm + mi * 16 + quad * 4) * 512 + g64 + colv;
#pragma unroll
          for (int r = 0; r < 4; ++r, idx += 512) {
            float v = acc[mi][nj][r] + bet;
            int lr = wm + mi * 16 + quad * 4 + r;
            Vx[lr * 64 + (colv ^ (((lr >> 2) & 3) << 4))] = v;
            ((unsigned short*)Ov)[idx] = f2bf(v);
          }
        }
      }
    }
    __syncthreads();
    if (!wn) {
      // K-waves: S1 = sum K*V, S2 = sum K, lred = sum K^2 (Frobenius)
      float s1[4] = {0.f, 0.f, 0.f, 0.f};
      float s2[4] = {0.f, 0.f, 0.f, 0.f};
#pragma unroll
      for (int mi = 0; mi < 4; ++mi) {
#pragma unroll
        for (int nj = 0; nj < 4; ++nj) {
          const int colv = nj * 16 + l15;
          const float bet = beta[g64 + colv];         // betak
#pragma unroll
          for (int r = 0; r < 4; ++r) {
            float v = acc[mi][nj][r] + bet;
            lred += v * v;
            int lr = wm + mi * 16 + quad * 4 + r;
            float vv = Vx[lr * 64 + (colv ^ (((lr >> 2) & 3) << 4))];
            s1[nj] += v * vv;
            s2[nj] += v;
          }
        }
      }
#pragma unroll
      for (int nj = 0; nj < 4; ++nj) {
        s1[nj] += __shfl_xor(s1[nj], 16); s1[nj] += __shfl_xor(s1[nj], 32);
        s2[nj] += __shfl_xor(s2[nj], 16); s2[nj] += __shfl_xor(s2[nj], 32);
      }
      if (quad == 0) {
#pragma unroll
        for (int nj = 0; nj < 4; ++nj) {
          atomicAdd(&S1[g64 + nj * 16 + l15], s1[nj]);
          atomicAdd(&S2[g64 + nj * 16 + l15], s2[nj]);
        }
      }
    }
  } else if constexpr (MODE == M_F1) {
    // transposed mapping: row = m0+wm+mi*16+l15 ; col = n0+wn+nj*16+quad*4+r
#pragma unroll
    for (int mi = 0; mi < 4; ++mi) {
      const size_t rowbase = (size_t)(m0 + wm + mi * 16 + l15) * N;
#pragma unroll
      for (int nj = 0; nj < 4; ++nj) {
        const int c0 = n0 + wn + nj * 16 + quad * 4;
        const float4 bet = *(const float4*)(beta + c0);
        float g[4];
        const float bv[4] = {bet.x, bet.y, bet.z, bet.w};
#pragma unroll
        for (int r = 0; r < 4; ++r) {
          float v = acc[mi][nj][r] + bv[r];
          // gelu(v) = v * sigmoid(2c(v + a v^3)), c=sqrt(2/pi), a=0.044715
          float t2 = v * v;
          float y2 = 1.5957691216f * v * __builtin_fmaf(0.044715f, t2, 1.0f);
          float e = __expf(y2);
          float rr = __builtin_amdgcn_rcpf(e + 1.0f);
          g[r] = v - v * rr;               // v*(1 - 1/(e+1)) = v*sigmoid(y2)
        }
        union { __hip_bfloat162 b; unsigned u; } p0, p1;
        p0.b = __float22bfloat162_rn(make_float2(g[0], g[1]));
        p1.b = __float22bfloat162_rn(make_float2(g[2], g[3]));
        uint2 st; st.x = p0.u; st.y = p1.u;
        *(uint2*)((unsigned short*)Ov + rowbase + c0) = st;
      }
    }
  } else {
#pragma unroll
    for (int mi = 0; mi < 4; ++mi) {
#pragma unroll
      for (int nj = 0; nj < 4; ++nj) {
        const int col = n0 + wn + nj * 16 + l15;
        const float bet = beta[col];
        size_t idx = (size_t)(m0 + wm + mi * 16 + quad * 4) * N + col;
#pragma unroll
        for (int r = 0; r < 4; ++r, idx += N) {
          float v = acc[mi][nj][r] + bet;
          if constexpr (MODE == M_Q) {
            lred += v * v;
            ((unsigned short*)Ov)[idx] = f2bf(v);
          } else if constexpr (MODE == M_H) {
            ((float*)Ov)[idx] = v + src[idx];
          } else {
            ((float*)Ov)[idx] += v;
          }
        }
      }
    }
  }
  if constexpr (MODE == M_Q || MODE == M_KV) {
    // M_KV: lred is 0 on V-waves; all waves join the reduction uniformly
#pragma unroll
    for (int off = 32; off > 0; off >>= 1) lred += __shfl_xor(lred, off);
    if (lane == 0) red[wave] = lred;
    __syncthreads();
    if (t == 0) atomicAdd(scal, red[0] + red[1] + red[2] + red[3]);
  }
}

// ---- elementwise attention; reads Q bf16 + V bf16, writes attn bf16 in place
__launch_bounds__(256)
__global__ void attn_k(unsigned short* __restrict__ Qb, const unsigned short* __restrict__ Vb,
                       const float* __restrict__ S1, const float* __restrict__ S2,
                       const float* __restrict__ sqq, const float* __restrict__ skk) {
  int t = threadIdx.x;
  int row = blockIdx.x * 4 + (t >> 6);
  int lane = t & 63;
  int c = lane * 8;
  float inv = rsqrtf(sqq[0] * skk[0]);
  const float Nf = (float)NROWS;
  unsigned short* qp = Qb + (size_t)row * 512 + c;
  uint4 qu = *(const uint4*)qp;
  float q[8];
  q[0] = bf2f((unsigned short)(qu.x & 0xffff)); q[1] = bf2f((unsigned short)(qu.x >> 16));
  q[2] = bf2f((unsigned short)(qu.y & 0xffff)); q[3] = bf2f((unsigned short)(qu.y >> 16));
  q[4] = bf2f((unsigned short)(qu.z & 0xffff)); q[5] = bf2f((unsigned short)(qu.z >> 16));
  q[6] = bf2f((unsigned short)(qu.w & 0xffff)); q[7] = bf2f((unsigned short)(qu.w >> 16));
  const unsigned short* vp = Vb + (size_t)row * 512 + c;
  uint4 vu = *(const uint4*)vp;
  float vv[8];
  vv[0] = bf2f((unsigned short)(vu.x & 0xffff)); vv[1] = bf2f((unsigned short)(vu.x >> 16));
  vv[2] = bf2f((unsigned short)(vu.y & 0xffff)); vv[3] = bf2f((unsigned short)(vu.y >> 16));
  vv[4] = bf2f((unsigned short)(vu.z & 0xffff)); vv[5] = bf2f((unsigned short)(vu.z >> 16));
  vv[6] = bf2f((unsigned short)(vu.w & 0xffff)); vv[7] = bf2f((unsigned short)(vu.w >> 16));
  float4 s10 = *(const float4*)(S1 + c), s11 = *(const float4*)(S1 + c + 4);
  float4 s20 = *(const float4*)(S2 + c), s21 = *(const float4*)(S2 + c + 4);
  float s1v[8] = {s10.x, s10.y, s10.z, s10.w, s11.x, s11.y, s11.z, s11.w};
  float s2v[8] = {s20.x, s20.y, s20.z, s20.w, s21.x, s21.y, s21.z, s21.w};
  float part = 0.f;
#pragma unroll
  for (int i = 0; i < 8; ++i) part += q[i] * s2v[i];
  part += __shfl_xor(part, 1);
  part += __shfl_xor(part, 2);
  part += __shfl_xor(part, 4);
  float rn = 1.0f / (inv * part + Nf);
  unsigned pk[4];
#pragma unroll
  for (int i = 0; i < 4; ++i) {
    float o0 = (q[2 * i] * s1v[2 * i] * inv + vv[2 * i] * Nf) * rn;
    float o1 = (q[2 * i + 1] * s1v[2 * i + 1] * inv + vv[2 * i + 1] * Nf) * rn;
    pk[i] = (unsigned)f2bf(o0) | ((unsigned)f2bf(o1) << 16);
  }
  uint4 u; u.x = pk[0]; u.y = pk[1]; u.z = pk[2]; u.w = pk[3];
  *(uint4*)qp = u;
}

extern "C" void kernel_launch(void* const* d_in, const int* in_sizes, int n_in,
                              void* d_out, int out_size, void* d_ws, size_t ws_size,
                              hipStream_t stream) {
  const float* query   = (const float*)d_in[0];
  const float* source  = (const float*)d_in[1];
  const float* Wq      = (const float*)d_in[2];
  const float* bq      = (const float*)d_in[3];
  const float* Wk      = (const float*)d_in[4];
  const float* bk      = (const float*)d_in[5];
  const float* Wv      = (const float*)d_in[6];
  const float* bv      = (const float*)d_in[7];
  const float* Wh      = (const float*)d_in[8];
  const float* bh      = (const float*)d_in[9];
  const float* ln_kv_g = (const float*)d_in[10];
  const float* ln_kv_b = (const float*)d_in[11];
  const float* ln_q_g  = (const float*)d_in[12];
  const float* ln_q_b  = (const float*)d_in[13];
  const float* ln2_g   = (const float*)d_in[14];
  const float* ln2_b   = (const float*)d_in[15];
  const float* W1      = (const float*)d_in[16];
  const float* b1      = (const float*)d_in[17];
  const float* W2      = (const float*)d_in[18];
  const float* b2      = (const float*)d_in[19];
  float* out = (float*)d_out;

  const size_t MB = 1024 * 1024;
  char* w = (char*)d_ws;
  unsigned short* Qn = (unsigned short*)(w + 0 * MB);    // 64 MB bf16 normalized query
  unsigned short* Sn = (unsigned short*)(w + 64 * MB);   // 64 MB bf16 normalized source
  unsigned short* Qb = (unsigned short*)(w + 128 * MB);  // 64 MB bf16 Q (then attn, in place)
  unsigned short* Vb = (unsigned short*)(w + 192 * MB);  // 64 MB bf16 V (K never hits HBM)
  unsigned short* Hn = (unsigned short*)(w + 256 * MB);  // 64 MB bf16 LN(h)
  unsigned short* Tb = (unsigned short*)(w + 0 * MB);    // 256 MB bf16 gelu out (overlays Qn/Sn/Qb/Vb, all dead by F1)
  char* wt = w + 384 * MB;
  unsigned short* Wqt = (unsigned short*)wt;             // 512 KB each
  unsigned short* Wkt = Wqt + 512 * 512;                 // Wkt rows 0..511,
  unsigned short* Wvt = Wkt + 512 * 512;                 //   Wvt rows 512..1023 (adjacent)
  unsigned short* Wht = Wvt + 512 * 512;
  unsigned short* W1t = Wht + 512 * 512;                 // 2 MB
  unsigned short* W2t = W1t + 512 * 2048;                // 2 MB
  float* betaq = (float*)(W2t + 2048 * 512);
  float* betak = betaq + 512;                            // betak|betav adjacent
  float* betav = betak + 512;
  float* betaf = betav + 512;                            // 2048
  float* S1 = betaf + 2048;                              // 512
  float* S2 = S1 + 512;                                  // 512
  float* SQQ = S2 + 512;
  float* SKK = SQQ + 1;

  hipMemsetAsync(S1, 0, (512 + 512 + 2) * sizeof(float), stream);

  dim3 blk(256);
  normcast_k<<<NROWS / 4, blk, 0, stream>>>(query, Qn);
  normcast_k<<<NROWS / 4, blk, 0, stream>>>(source, Sn);
  transbf_k<<<dim3(16, 16), blk, 0, stream>>>(Wq, ln_q_g, Wqt, 512, 512);
  transbf_k<<<dim3(16, 16), blk, 0, stream>>>(Wk, ln_kv_g, Wkt, 512, 512);
  transbf_k<<<dim3(16, 16), blk, 0, stream>>>(Wv, ln_kv_g, Wvt, 512, 512);
  transbf_k<<<dim3(16, 16), blk, 0, stream>>>(Wh, nullptr, Wht, 512, 512);
  transbf_k<<<dim3(64, 16), blk, 0, stream>>>(W1, ln2_g, W1t, 512, 2048);
  transbf_k<<<dim3(16, 64), blk, 0, stream>>>(W2, nullptr, W2t, 2048, 512);
  betacalc_k<<<2, blk, 0, stream>>>(Wq, ln_q_b, bq, betaq, 512, 512);
  betacalc_k<<<2, blk, 0, stream>>>(Wk, ln_kv_b, bk, betak, 512, 512);
  betacalc_k<<<2, blk, 0, stream>>>(Wv, ln_kv_b, bv, betav, 512, 512);
  betacalc_k<<<8, blk, 0, stream>>>(W1, ln2_b, b1, betaf, 512, 2048);

  dim3 g512(4, 512);
  mm_k<M_Q><<<g512, blk, 0, stream>>>(Qn, Wqt, Qb, betaq, nullptr, SQQ, nullptr, nullptr, 512, 512);
  // paired K/V GEMM: 8 column-groups of 64; computes V, S1, S2, SKK; K stays on-chip
  mm_k<M_KV><<<dim3(8, 512), blk, 0, stream>>>(Sn, Wkt, Vb, betak, nullptr, SKK, S1, S2, 512, 512);
  attn_k<<<NROWS / 4, blk, 0, stream>>>(Qb, Vb, S1, S2, SQQ, SKK);
  mm_k<M_H><<<g512, blk, 0, stream>>>(Qb, Wht, out, bh, source, nullptr, nullptr, nullptr, 512, 512);
  normcast_k<<<NROWS / 4, blk, 0, stream>>>(out, Hn);
  dim3 g2048(16, 512);
  mm_k<M_F1><<<g2048, blk, 0, stream>>>(Hn, W1t, Tb, betaf, nullptr, nullptr, nullptr, nullptr, 2048, 512);
  mm_k<M_F2><<<g512, blk, 0, stream>>>(Tb, W2t, out, b2, nullptr, nullptr, nullptr, nullptr, 512, 2048);
}

// Round 6
// 1586.462 us; speedup vs baseline: 1.0895x; 1.0895x over previous
//
#include <hip/hip_runtime.h>
#include <hip/hip_bf16.h>

#define NROWS 65536
#define LN_EPS 1e-5f

typedef __attribute__((ext_vector_type(8))) short bf16x8;
typedef __attribute__((ext_vector_type(4))) float f32x4;

__device__ __forceinline__ float bf2f(unsigned short u) {
  union { unsigned u; float f; } c; c.u = ((unsigned)u) << 16; return c.f;
}
__device__ __forceinline__ unsigned short f2bf(float f) {
  union { float f; unsigned u; } c; c.f = f;
  return (unsigned short)((c.u + 0x7fffu + ((c.u >> 16) & 1u)) >> 16);
}

// ---- row LN stats + normalize + cast to bf16 ------------------------------
__launch_bounds__(256)
__global__ void normcast_k(const float* __restrict__ x, unsigned short* __restrict__ o) {
  int t = threadIdx.x;
  int row = blockIdx.x * 4 + (t >> 6);
  int lane = t & 63;
  const float* p = x + (size_t)row * 512 + lane * 8;
  float4 a = *(const float4*)p;
  float4 b = *(const float4*)(p + 4);
  float s = a.x + a.y + a.z + a.w + b.x + b.y + b.z + b.w;
  float q = a.x*a.x + a.y*a.y + a.z*a.z + a.w*a.w
          + b.x*b.x + b.y*b.y + b.z*b.z + b.w*b.w;
#pragma unroll
  for (int off = 1; off < 64; off <<= 1) {
    s += __shfl_xor(s, off);
    q += __shfl_xor(q, off);
  }
  float mean = s * (1.0f / 512.0f);
  float r = rsqrtf(q * (1.0f / 512.0f) - mean * mean + LN_EPS);
  float va[8] = {a.x, a.y, a.z, a.w, b.x, b.y, b.z, b.w};
  unsigned pk[4];
#pragma unroll
  for (int i = 0; i < 4; ++i) {
    unsigned lo = f2bf((va[2 * i] - mean) * r);
    unsigned hi = f2bf((va[2 * i + 1] - mean) * r);
    pk[i] = lo | (hi << 16);
  }
  uint4 u; u.x = pk[0]; u.y = pk[1]; u.z = pk[2]; u.w = pk[3];
  *(uint4*)(o + (size_t)row * 512 + lane * 8) = u;
}

// ---- transpose + optional per-K-row scale, fp32 -> bf16 -------------------
__launch_bounds__(256)
__global__ void transbf_k(const float* __restrict__ W, const float* __restrict__ g,
                          unsigned short* __restrict__ Wt, int K, int N) {
  __shared__ float tile[32][33];
  int tx = threadIdx.x & 31, ty = threadIdx.x >> 5;
  int n0 = blockIdx.x * 32, k0 = blockIdx.y * 32;
#pragma unroll
  for (int i = 0; i < 4; ++i) {
    int k = k0 + ty + i * 8;
    float gg = g ? g[k] : 1.0f;
    tile[ty + i * 8][tx] = gg * W[(size_t)k * N + n0 + tx];
  }
  __syncthreads();
#pragma unroll
  for (int i = 0; i < 4; ++i) {
    int n = n0 + ty + i * 8;
    Wt[(size_t)n * K + k0 + tx] = f2bf(tile[tx][ty + i * 8]);
  }
}

// ---- beta[n] = sum_k b[k]*W[k,n] + bias[n] --------------------------------
__launch_bounds__(256)
__global__ void betacalc_k(const float* __restrict__ W, const float* __restrict__ b,
                           const float* __restrict__ bias, float* __restrict__ beta,
                           int K, int N) {
  int n = blockIdx.x * 256 + threadIdx.x;
  float s = 0.f;
  for (int k = 0; k < K; ++k) s += b[k] * W[(size_t)k * N + n];
  beta[n] = s + bias[n];
}

#define M_Q  0  // out bf16, reduce sum(v^2) -> scal
#define M_KV 1  // paired K/V 64-col groups; V->bf16 out, K only reduced (S1,S2,scal)
#define M_H  3  // out fp32 = acc + beta + src (residual)
#define M_F1 4  // out bf16 = gelu(acc + beta)
#define M_F2 5  // out fp32 += acc + beta

// ============================================================================
// 8-phase 256x256/BK=64/8-wave GEMM (T3+T4+T5): raw barriers, counted vmcnt,
// double-buffered 128KB LDS. Used for Q, H, F1, F2 (simple epilogues).
// Per K-tile: 4 phases {ds_read quadrant | prefetch-stage -> barrier ->
// setprio(1) 16 MFMA setprio(0) -> barrier}; one vmcnt(0) per tile at P3.
// Accumulation order per element identical to the old kernel (kt0 then kt1
// within each 64-K tile, tiles sequential) -> bitwise-same results.
// ============================================================================
template <int MODE>
__launch_bounds__(512, 1)
__global__ void mm8_k(const unsigned short* __restrict__ A,
                      const unsigned short* __restrict__ Bt,
                      void* __restrict__ Ov,
                      const float* __restrict__ beta,
                      const float* __restrict__ src,
                      float* __restrict__ scal,
                      int N, int K) {
  __shared__ __align__(16) unsigned short LDS[65536];  // As[2][256][64] | Bs[2][256][64]
  __shared__ float red[8];
  const int t = threadIdx.x;
  const int lane = t & 63;
  const int wave = t >> 6;
  const int quad = lane >> 4;
  const int l15 = lane & 15;
  const int l7 = lane & 7;
  const int wrow = (wave >> 2) * 128;   // 2 M-waves x 4 N-waves
  const int wcol = (wave & 3) * 64;

  // XCD-chunked bijective swizzle (nwg % 8 == 0 for all grids used)
  const unsigned gx = gridDim.x;
  unsigned bid = blockIdx.y * gx + blockIdx.x;
  const unsigned cpx = (gx * gridDim.y) >> 3;
  bid = (bid & 7u) * cpx + (bid >> 3);
  const int m0 = (int)(bid / gx) * 256;
  const int n0 = (int)(bid % gx) * 256;

  // staging thread map: 512 threads x 16B = 8KB/instr = 64 rows x 64 cols
  const int srow_t = t >> 3;            // row within 64-row chunk
  const int sslot = t & 7;              // 16B slot within row
  const int sxor = (sslot ^ (srow_t & 7)) * 8;  // pre-swizzled source k-offset

  f32x4 acc[8][4];
#pragma unroll
  for (int i = 0; i < 8; ++i)
#pragma unroll
    for (int j = 0; j < 4; ++j) acc[i][j] = (f32x4){0.f, 0.f, 0.f, 0.f};

  const int NT = K >> 6;

  for (int tt = 0; tt < NT; ++tt) {
    const int buf = tt & 1;
    const unsigned short* As = LDS + buf * 16384;
    const unsigned short* Bs = LDS + 32768 + buf * 16384;

    if (tt == 0) {
      // prologue: stage tile 0 into buf 0, full drain
#pragma unroll
      for (int c = 0; c < 4; ++c) {
        const unsigned short* ga = A + (size_t)(m0 + c * 64 + srow_t) * K + sxor;
        __builtin_amdgcn_global_load_lds(
            (const __attribute__((address_space(1))) void*)ga,
            (__attribute__((address_space(3))) void*)(LDS + (c * 64 + wave * 8) * 64), 16, 0, 0);
      }
#pragma unroll
      for (int c = 0; c < 4; ++c) {
        const unsigned short* gb = Bt + (size_t)(n0 + c * 64 + srow_t) * K + sxor;
        __builtin_amdgcn_global_load_lds(
            (const __attribute__((address_space(1))) void*)gb,
            (__attribute__((address_space(3))) void*)(LDS + 32768 + (c * 64 + wave * 8) * 64), 16, 0, 0);
      }
      asm volatile("s_waitcnt vmcnt(0)" ::: "memory");
      __builtin_amdgcn_s_barrier();
    }

    bf16x8 a0[4], a1[4], bfr[4];
    // ---- P0: read A(mi0-3,kt0) + B(kt0); stage next-tile A ----
#pragma unroll
    for (int x = 0; x < 4; ++x) {
      a0[x]  = *(const bf16x8*)(As + (wrow + x * 16 + l15) * 64 + ((quad ^ l7) * 8));
      bfr[x] = *(const bf16x8*)(Bs + (wcol + x * 16 + l15) * 64 + ((quad ^ l7) * 8));
    }
    if (tt + 1 < NT) {
#pragma unroll
      for (int c = 0; c < 4; ++c) {
        const unsigned short* ga = A + (size_t)(m0 + c * 64 + srow_t) * K + (tt + 1) * 64 + sxor;
        __builtin_amdgcn_global_load_lds(
            (const __attribute__((address_space(1))) void*)ga,
            (__attribute__((address_space(3))) void*)(LDS + (buf ^ 1) * 16384 + (c * 64 + wave * 8) * 64), 16, 0, 0);
      }
    }
    __builtin_amdgcn_s_barrier();
    __builtin_amdgcn_s_setprio(1);
#pragma unroll
    for (int mi = 0; mi < 4; ++mi)
#pragma unroll
      for (int nj = 0; nj < 4; ++nj)
        acc[mi][nj] = __builtin_amdgcn_mfma_f32_16x16x32_bf16(a0[mi], bfr[nj], acc[mi][nj], 0, 0, 0);
    __builtin_amdgcn_s_setprio(0);
    __builtin_amdgcn_s_barrier();

    // ---- P1: read A(mi4-7,kt0); stage next-tile B ----
#pragma unroll
    for (int x = 0; x < 4; ++x)
      a1[x] = *(const bf16x8*)(As + (wrow + 64 + x * 16 + l15) * 64 + ((quad ^ l7) * 8));
    if (tt + 1 < NT) {
#pragma unroll
      for (int c = 0; c < 4; ++c) {
        const unsigned short* gb = Bt + (size_t)(n0 + c * 64 + srow_t) * K + (tt + 1) * 64 + sxor;
        __builtin_amdgcn_global_load_lds(
            (const __attribute__((address_space(1))) void*)gb,
            (__attribute__((address_space(3))) void*)(LDS + 32768 + (buf ^ 1) * 16384 + (c * 64 + wave * 8) * 64), 16, 0, 0);
      }
    }
    __builtin_amdgcn_s_barrier();
    __builtin_amdgcn_s_setprio(1);
#pragma unroll
    for (int mi = 0; mi < 4; ++mi)
#pragma unroll
      for (int nj = 0; nj < 4; ++nj)
        acc[4 + mi][nj] = __builtin_amdgcn_mfma_f32_16x16x32_bf16(a1[mi], bfr[nj], acc[4 + mi][nj], 0, 0, 0);
    __builtin_amdgcn_s_setprio(0);
    __builtin_amdgcn_s_barrier();

    // ---- P2: read A(mi0-3,kt1) + B(kt1) ----
#pragma unroll
    for (int x = 0; x < 4; ++x) {
      a0[x]  = *(const bf16x8*)(As + (wrow + x * 16 + l15) * 64 + (((4 + quad) ^ l7) * 8));
      bfr[x] = *(const bf16x8*)(Bs + (wcol + x * 16 + l15) * 64 + (((4 + quad) ^ l7) * 8));
    }
    __builtin_amdgcn_s_barrier();
    __builtin_amdgcn_s_setprio(1);
#pragma unroll
    for (int mi = 0; mi < 4; ++mi)
#pragma unroll
      for (int nj = 0; nj < 4; ++nj)
        acc[mi][nj] = __builtin_amdgcn_mfma_f32_16x16x32_bf16(a0[mi], bfr[nj], acc[mi][nj], 0, 0, 0);
    __builtin_amdgcn_s_setprio(0);
    __builtin_amdgcn_s_barrier();

    // ---- P3: read A(mi4-7,kt1); vmcnt drain for next tile ----
#pragma unroll
    for (int x = 0; x < 4; ++x)
      a1[x] = *(const bf16x8*)(As + (wrow + 64 + x * 16 + l15) * 64 + (((4 + quad) ^ l7) * 8));
    __builtin_amdgcn_s_barrier();
    __builtin_amdgcn_s_setprio(1);
#pragma unroll
    for (int mi = 0; mi < 4; ++mi)
#pragma unroll
      for (int nj = 0; nj < 4; ++nj)
        acc[4 + mi][nj] = __builtin_amdgcn_mfma_f32_16x16x32_bf16(a1[mi], bfr[nj], acc[4 + mi][nj], 0, 0, 0);
    __builtin_amdgcn_s_setprio(0);
    if (tt + 1 < NT) asm volatile("s_waitcnt vmcnt(0)" ::: "memory");
    __builtin_amdgcn_s_barrier();
  }

  // ---- epilogue ----
  float lred = 0.f;
#pragma unroll
  for (int mi = 0; mi < 8; ++mi) {
#pragma unroll
    for (int nj = 0; nj < 4; ++nj) {
      const int col = n0 + wcol + nj * 16 + l15;
      const float bet = beta[col];
      size_t idx = (size_t)(m0 + wrow + mi * 16 + quad * 4) * N + col;
#pragma unroll
      for (int r = 0; r < 4; ++r, idx += N) {
        float v = acc[mi][nj][r] + bet;
        if constexpr (MODE == M_Q) {
          lred += v * v;
          ((unsigned short*)Ov)[idx] = f2bf(v);
        } else if constexpr (MODE == M_H) {
          ((float*)Ov)[idx] = v + src[idx];
        } else if constexpr (MODE == M_F1) {
          float t2 = v * v;
          float y2 = 1.5957691216f * v * __builtin_fmaf(0.044715f, t2, 1.0f);
          float e = __expf(y2);
          float rr = __builtin_amdgcn_rcpf(e + 1.0f);
          ((unsigned short*)Ov)[idx] = f2bf(v - v * rr);
        } else {
          ((float*)Ov)[idx] += v;
        }
      }
    }
  }
  if constexpr (MODE == M_Q) {
#pragma unroll
    for (int off = 32; off > 0; off >>= 1) lred += __shfl_xor(lred, off);
    if (lane == 0) red[wave] = lred;
    __syncthreads();
    if (t == 0) {
      float s = 0.f;
#pragma unroll
      for (int i = 0; i < 8; ++i) s += red[i];
      atomicAdd(scal, s);
    }
  }
}

// ---- old 128x128 GEMM, kept for the fused K/V mode ------------------------
template <int MODE>
__launch_bounds__(256)
__global__ void mm_k(const unsigned short* __restrict__ A,
                     const unsigned short* __restrict__ Bt,
                     void* __restrict__ Ov,
                     const float* __restrict__ beta,
                     const float* __restrict__ src,
                     float* __restrict__ scal,
                     float* __restrict__ S1,
                     float* __restrict__ S2,
                     int N, int K) {
  __shared__ __align__(16) unsigned short AsBs[2 * 128 * 64];
  __shared__ float red[4];
  unsigned short* As = AsBs;
  unsigned short* Bs = AsBs + 128 * 64;
  const int t = threadIdx.x;
  const int lane = t & 63;
  const int wave = t >> 6;

  const unsigned gx = gridDim.x;
  unsigned bid = blockIdx.y * gx + blockIdx.x;
  const unsigned cpx = (gx * gridDim.y) >> 3;
  bid = (bid & 7u) * cpx + (bid >> 3);
  const int m0 = (int)(bid / gx) * 128;
  const int n0 = (int)(bid % gx) * 128;
  const int g64 = n0 >> 1;

  const int srow = lane >> 3;
  const int sxor = ((lane & 7) ^ srow) * 8;
  const int wm = (wave >> 1) * 64;
  const int wn = (wave & 1) * 64;
  const int quad = lane >> 4;
  const int l15 = lane & 15;
  const int l7 = lane & 7;

  f32x4 acc[4][4];
#pragma unroll
  for (int i = 0; i < 4; ++i)
#pragma unroll
    for (int j = 0; j < 4; ++j) acc[i][j] = (f32x4){0.f, 0.f, 0.f, 0.f};

  for (int k0 = 0; k0 < K; k0 += 64) {
    __syncthreads();
#pragma unroll
    for (int i = 0; i < 4; ++i) {
      int c = wave * 4 + i;
      int grow = c * 8 + srow;
      const unsigned short* ga = A + (size_t)(m0 + grow) * K + k0 + sxor;
      const unsigned short* gb;
      if constexpr (MODE == M_KV) {
        int btrow = (c < 8) ? (g64 + grow) : (512 - 64 + g64 + grow);
        gb = Bt + (size_t)btrow * K + k0 + sxor;
      } else {
        gb = Bt + (size_t)(n0 + grow) * K + k0 + sxor;
      }
      __builtin_amdgcn_global_load_lds(
          (const __attribute__((address_space(1))) void*)ga,
          (__attribute__((address_space(3))) void*)(As + c * 512), 16, 0, 0);
      __builtin_amdgcn_global_load_lds(
          (const __attribute__((address_space(1))) void*)gb,
          (__attribute__((address_space(3))) void*)(Bs + c * 512), 16, 0, 0);
    }
    __syncthreads();
#pragma unroll
    for (int kt = 0; kt < 2; ++kt) {
      const int pb = ((kt * 4 + quad) ^ l7) * 8;
      bf16x8 af[4], bfr[4];
#pragma unroll
      for (int x = 0; x < 4; ++x) {
        af[x]  = *(const bf16x8*)(As + (wm + x * 16 + l15) * 64 + pb);
        bfr[x] = *(const bf16x8*)(Bs + (wn + x * 16 + l15) * 64 + pb);
      }
#pragma unroll
      for (int mi = 0; mi < 4; ++mi)
#pragma unroll
        for (int nj = 0; nj < 4; ++nj)
          acc[mi][nj] = __builtin_amdgcn_mfma_f32_16x16x32_bf16(
              af[mi], bfr[nj], acc[mi][nj], 0, 0, 0);
    }
  }

  float lred = 0.f;
  if constexpr (MODE == M_KV) {
    float* Vx = (float*)AsBs;
    __syncthreads();
    if (wn) {
#pragma unroll
      for (int mi = 0; mi < 4; ++mi) {
#pragma unroll
        for (int nj = 0; nj < 4; ++nj) {
          const int colv = nj * 16 + l15;
          const float bet = beta[512 + g64 + colv];
          size_t idx = (size_t)(m0 + wm + mi * 16 + quad * 4) * 512 + g64 + colv;
#pragma unroll
          for (int r = 0; r < 4; ++r, idx += 512) {
            float v = acc[mi][nj][r] + bet;
            int lr = wm + mi * 16 + quad * 4 + r;
            Vx[lr * 64 + (colv ^ (((lr >> 2) & 3) << 4))] = v;
            ((unsigned short*)Ov)[idx] = f2bf(v);
          }
        }
      }
    }
    __syncthreads();
    if (!wn) {
      float s1[4] = {0.f, 0.f, 0.f, 0.f};
      float s2[4] = {0.f, 0.f, 0.f, 0.f};
#pragma unroll
      for (int mi = 0; mi < 4; ++mi) {
#pragma unroll
        for (int nj = 0; nj < 4; ++nj) {
          const int colv = nj * 16 + l15;
          const float bet = beta[g64 + colv];
#pragma unroll
          for (int r = 0; r < 4; ++r) {
            float v = acc[mi][nj][r] + bet;
            lred += v * v;
            int lr = wm + mi * 16 + quad * 4 + r;
            float vv = Vx[lr * 64 + (colv ^ (((lr >> 2) & 3) << 4))];
            s1[nj] += v * vv;
            s2[nj] += v;
          }
        }
      }
#pragma unroll
      for (int nj = 0; nj < 4; ++nj) {
        s1[nj] += __shfl_xor(s1[nj], 16); s1[nj] += __shfl_xor(s1[nj], 32);
        s2[nj] += __shfl_xor(s2[nj], 16); s2[nj] += __shfl_xor(s2[nj], 32);
      }
      if (quad == 0) {
#pragma unroll
        for (int nj = 0; nj < 4; ++nj) {
          atomicAdd(&S1[g64 + nj * 16 + l15], s1[nj]);
          atomicAdd(&S2[g64 + nj * 16 + l15], s2[nj]);
        }
      }
    }
  }
  if constexpr (MODE == M_KV) {
#pragma unroll
    for (int off = 32; off > 0; off >>= 1) lred += __shfl_xor(lred, off);
    if (lane == 0) red[wave] = lred;
    __syncthreads();
    if (t == 0) atomicAdd(scal, red[0] + red[1] + red[2] + red[3]);
  }
}

// ---- elementwise attention ------------------------------------------------
__launch_bounds__(256)
__global__ void attn_k(unsigned short* __restrict__ Qb, const unsigned short* __restrict__ Vb,
                       const float* __restrict__ S1, const float* __restrict__ S2,
                       const float* __restrict__ sqq, const float* __restrict__ skk) {
  int t = threadIdx.x;
  int row = blockIdx.x * 4 + (t >> 6);
  int lane = t & 63;
  int c = lane * 8;
  float inv = rsqrtf(sqq[0] * skk[0]);
  const float Nf = (float)NROWS;
  unsigned short* qp = Qb + (size_t)row * 512 + c;
  uint4 qu = *(const uint4*)qp;
  float q[8];
  q[0] = bf2f((unsigned short)(qu.x & 0xffff)); q[1] = bf2f((unsigned short)(qu.x >> 16));
  q[2] = bf2f((unsigned short)(qu.y & 0xffff)); q[3] = bf2f((unsigned short)(qu.y >> 16));
  q[4] = bf2f((unsigned short)(qu.z & 0xffff)); q[5] = bf2f((unsigned short)(qu.z >> 16));
  q[6] = bf2f((unsigned short)(qu.w & 0xffff)); q[7] = bf2f((unsigned short)(qu.w >> 16));
  const unsigned short* vp = Vb + (size_t)row * 512 + c;
  uint4 vu = *(const uint4*)vp;
  float vv[8];
  vv[0] = bf2f((unsigned short)(vu.x & 0xffff)); vv[1] = bf2f((unsigned short)(vu.x >> 16));
  vv[2] = bf2f((unsigned short)(vu.y & 0xffff)); vv[3] = bf2f((unsigned short)(vu.y >> 16));
  vv[4] = bf2f((unsigned short)(vu.z & 0xffff)); vv[5] = bf2f((unsigned short)(vu.z >> 16));
  vv[6] = bf2f((unsigned short)(vu.w & 0xffff)); vv[7] = bf2f((unsigned short)(vu.w >> 16));
  float4 s10 = *(const float4*)(S1 + c), s11 = *(const float4*)(S1 + c + 4);
  float4 s20 = *(const float4*)(S2 + c), s21 = *(const float4*)(S2 + c + 4);
  float s1v[8] = {s10.x, s10.y, s10.z, s10.w, s11.x, s11.y, s11.z, s11.w};
  float s2v[8] = {s20.x, s20.y, s20.z, s20.w, s21.x, s21.y, s21.z, s21.w};
  float part = 0.f;
#pragma unroll
  for (int i = 0; i < 8; ++i) part += q[i] * s2v[i];
  part += __shfl_xor(part, 1);
  part += __shfl_xor(part, 2);
  part += __shfl_xor(part, 4);
  float rn = 1.0f / (inv * part + Nf);
  unsigned pk[4];
#pragma unroll
  for (int i = 0; i < 4; ++i) {
    float o0 = (q[2 * i] * s1v[2 * i] * inv + vv[2 * i] * Nf) * rn;
    float o1 = (q[2 * i + 1] * s1v[2 * i + 1] * inv + vv[2 * i + 1] * Nf) * rn;
    pk[i] = (unsigned)f2bf(o0) | ((unsigned)f2bf(o1) << 16);
  }
  uint4 u; u.x = pk[0]; u.y = pk[1]; u.z = pk[2]; u.w = pk[3];
  *(uint4*)qp = u;
}

extern "C" void kernel_launch(void* const* d_in, const int* in_sizes, int n_in,
                              void* d_out, int out_size, void* d_ws, size_t ws_size,
                              hipStream_t stream) {
  const float* query   = (const float*)d_in[0];
  const float* source  = (const float*)d_in[1];
  const float* Wq      = (const float*)d_in[2];
  const float* bq      = (const float*)d_in[3];
  const float* Wk      = (const float*)d_in[4];
  const float* bk      = (const float*)d_in[5];
  const float* Wv      = (const float*)d_in[6];
  const float* bv      = (const float*)d_in[7];
  const float* Wh      = (const float*)d_in[8];
  const float* bh      = (const float*)d_in[9];
  const float* ln_kv_g = (const float*)d_in[10];
  const float* ln_kv_b = (const float*)d_in[11];
  const float* ln_q_g  = (const float*)d_in[12];
  const float* ln_q_b  = (const float*)d_in[13];
  const float* ln2_g   = (const float*)d_in[14];
  const float* ln2_b   = (const float*)d_in[15];
  const float* W1      = (const float*)d_in[16];
  const float* b1      = (const float*)d_in[17];
  const float* W2      = (const float*)d_in[18];
  const float* b2      = (const float*)d_in[19];
  float* out = (float*)d_out;

  const size_t MB = 1024 * 1024;
  char* w = (char*)d_ws;
  unsigned short* Qn = (unsigned short*)(w + 0 * MB);
  unsigned short* Sn = (unsigned short*)(w + 64 * MB);
  unsigned short* Qb = (unsigned short*)(w + 128 * MB);
  unsigned short* Vb = (unsigned short*)(w + 192 * MB);
  unsigned short* Hn = (unsigned short*)(w + 256 * MB);
  unsigned short* Tb = (unsigned short*)(w + 0 * MB);   // overlays Qn/Sn/Qb/Vb (dead by F1)
  char* wt = w + 384 * MB;
  unsigned short* Wqt = (unsigned short*)wt;
  unsigned short* Wkt = Wqt + 512 * 512;
  unsigned short* Wvt = Wkt + 512 * 512;
  unsigned short* Wht = Wvt + 512 * 512;
  unsigned short* W1t = Wht + 512 * 512;
  unsigned short* W2t = W1t + 512 * 2048;
  float* betaq = (float*)(W2t + 2048 * 512);
  float* betak = betaq + 512;
  float* betav = betak + 512;
  float* betaf = betav + 512;
  float* S1 = betaf + 2048;
  float* S2 = S1 + 512;
  float* SQQ = S2 + 512;
  float* SKK = SQQ + 1;

  hipMemsetAsync(S1, 0, (512 + 512 + 2) * sizeof(float), stream);

  dim3 blk(256);
  dim3 blk8(512);
  normcast_k<<<NROWS / 4, blk, 0, stream>>>(query, Qn);
  normcast_k<<<NROWS / 4, blk, 0, stream>>>(source, Sn);
  transbf_k<<<dim3(16, 16), blk, 0, stream>>>(Wq, ln_q_g, Wqt, 512, 512);
  transbf_k<<<dim3(16, 16), blk, 0, stream>>>(Wk, ln_kv_g, Wkt, 512, 512);
  transbf_k<<<dim3(16, 16), blk, 0, stream>>>(Wv, ln_kv_g, Wvt, 512, 512);
  transbf_k<<<dim3(16, 16), blk, 0, stream>>>(Wh, nullptr, Wht, 512, 512);
  transbf_k<<<dim3(64, 16), blk, 0, stream>>>(W1, ln2_g, W1t, 512, 2048);
  transbf_k<<<dim3(16, 64), blk, 0, stream>>>(W2, nullptr, W2t, 2048, 512);
  betacalc_k<<<2, blk, 0, stream>>>(Wq, ln_q_b, bq, betaq, 512, 512);
  betacalc_k<<<2, blk, 0, stream>>>(Wk, ln_kv_b, bk, betak, 512, 512);
  betacalc_k<<<2, blk, 0, stream>>>(Wv, ln_kv_b, bv, betav, 512, 512);
  betacalc_k<<<8, blk, 0, stream>>>(W1, ln2_b, b1, betaf, 512, 2048);

  mm8_k<M_Q><<<dim3(2, 256), blk8, 0, stream>>>(Qn, Wqt, Qb, betaq, nullptr, SQQ, 512, 512);
  mm_k<M_KV><<<dim3(8, 512), blk, 0, stream>>>(Sn, Wkt, Vb, betak, nullptr, SKK, S1, S2, 512, 512);
  attn_k<<<NROWS / 4, blk, 0, stream>>>(Qb, Vb, S1, S2, SQQ, SKK);
  mm8_k<M_H><<<dim3(2, 256), blk8, 0, stream>>>(Qb, Wht, out, bh, source, nullptr, 512, 512);
  normcast_k<<<NROWS / 4, blk, 0, stream>>>(out, Hn);
  mm8_k<M_F1><<<dim3(8, 256), blk8, 0, stream>>>(Hn, W1t, Tb, betaf, nullptr, nullptr, 2048, 512);
  mm8_k<M_F2><<<dim3(2, 256), blk8, 0, stream>>>(Tb, W2t, out, b2, nullptr, nullptr, 512, 2048);
}